// Round 14
// baseline (114.259 us; speedup 1.0000x reference)
//
#include <hip/hip_runtime.h>
#include <hip/hip_bf16.h>
#include <math.h>

#define FEAT 384
#define FFN  768
#define ZDIM 384
#define HID  192
#define BB   4
#define NN   128
#define BN   (BB*NN)   // 512 rows

__device__ __forceinline__ float gelu_exact(float x) {
    return 0.5f * x * (1.0f + erff(x * 0.70710678118654752440f));
}

__device__ __forceinline__ float bflo(unsigned u) { return __uint_as_float(u << 16); }
__device__ __forceinline__ float bfhi(unsigned u) { return __uint_as_float(u & 0xFFFF0000u); }

template<bool F32>
__device__ __forceinline__ float ldg(const void* p, int i) {
    if constexpr (F32) return ((const float*)p)[i];
    return __uint_as_float(((unsigned)((const unsigned short*)p)[i]) << 16);
}
template<bool F32>
__device__ __forceinline__ void stg(void* p, size_t i, float v) {
    if constexpr (F32) ((float*)p)[i] = v;
    else ((__hip_bfloat16*)p)[i] = __float2bfloat16(v);
}

// 4-element weight vector: 16B load (fp32) / 8B load (bf16)
template<bool F32> struct V4;
template<> struct V4<true> {
    float4 a;
    __device__ __forceinline__ void load(const void* p, size_t off) {
        a = *(const float4*)((const float*)p + off);
    }
    __device__ __forceinline__ float g(int i) const { return (&a.x)[i]; }
};
template<> struct V4<false> {
    uint2 u;
    __device__ __forceinline__ void load(const void* p, size_t off) {
        u = *(const uint2*)((const unsigned short*)p + off);
    }
    __device__ __forceinline__ float g(int i) const {
        const unsigned w = (&u.x)[i >> 1];
        return (i & 1) ? bfhi(w) : bflo(w);
    }
};

__device__ __forceinline__ bool is_f32(const void* ln_w) {
    return ((const unsigned short*)ln_w)[0] == 0;
}

// ---- block reductions over 384 threads (6 wave64) ----
__device__ __forceinline__ float block_sum(float v, float* sm) {
    for (int o = 32; o > 0; o >>= 1) v += __shfl_down(v, o, 64);
    const int lane = threadIdx.x & 63, w = threadIdx.x >> 6;
    __syncthreads();
    if (lane == 0) sm[w] = v;
    __syncthreads();
    return sm[0] + sm[1] + sm[2] + sm[3] + sm[4] + sm[5];
}
__device__ __forceinline__ float block_max(float v, float* sm) {
    for (int o = 32; o > 0; o >>= 1) v = fmaxf(v, __shfl_down(v, o, 64));
    const int lane = threadIdx.x & 63, w = threadIdx.x >> 6;
    __syncthreads();
    if (lane == 0) sm[w] = v;
    __syncthreads();
    return fmaxf(fmaxf(fmaxf(sm[0], sm[1]), fmaxf(sm[2], sm[3])), fmaxf(sm[4], sm[5]));
}
// 4-wide block sum; sm must hold 24 floats
__device__ __forceinline__ void block_sum4(float v0, float v1, float v2, float v3,
                                           float* sm, float out[4]) {
    for (int o = 32; o > 0; o >>= 1) {
        v0 += __shfl_down(v0, o, 64);
        v1 += __shfl_down(v1, o, 64);
        v2 += __shfl_down(v2, o, 64);
        v3 += __shfl_down(v3, o, 64);
    }
    const int lane = threadIdx.x & 63, w = threadIdx.x >> 6;
    __syncthreads();
    if (lane == 0) { sm[w] = v0; sm[6 + w] = v1; sm[12 + w] = v2; sm[18 + w] = v3; }
    __syncthreads();
    #pragma unroll
    for (int q = 0; q < 4; q++)
        out[q] = sm[q*6] + sm[q*6+1] + sm[q*6+2] + sm[q*6+3] + sm[q*6+4] + sm[q*6+5];
}

// Shared pool (floats): xs 0 (1536), zs 1536 (1536), hid 3072 (768),
// gh 3840 (192) [contiguous after hid => 5th GEMM row], part 4032 (5760),
// sm 9792 (24). Total 9816 = 39.3 KB.
#define SM_TOTAL 9816

// Generic GEMM helper, 3-deep rotating weight staging:
// M rows from LDS (in[m*ldin + k]), 4 cols/thread, K-chunk KCH at base kb.
template<bool F32, int KCH, int M>
__device__ __forceinline__ void gemmMx4(
    const void* __restrict__ W, int ldw, int c0, int kb,
    const float* __restrict__ in, int ldin, float acc[M][4])
{
    constexpr int NB = KCH / 8;
    V4<F32> buf[3][8];
    #pragma unroll
    for (int j = 0; j < 8; j++) buf[0][j].load(W, (size_t)(kb + j) * ldw + c0);
    if (NB > 1) {
        #pragma unroll
        for (int j = 0; j < 8; j++) buf[1][j].load(W, (size_t)(kb + 8 + j) * ldw + c0);
    }
    #pragma unroll
    for (int b = 0; b < NB; b++) {
        const int cur = b % 3;
        if (b + 2 < NB) {
            const int nxt = (b + 2) % 3;
            #pragma unroll
            for (int j = 0; j < 8; j++)
                buf[nxt][j].load(W, (size_t)(kb + (b + 2) * 8 + j) * ldw + c0);
        }
        #pragma unroll
        for (int j = 0; j < 8; j++) {
            #pragma unroll
            for (int m = 0; m < M; m++) {
                const float xv = in[m * ldin + kb + b * 8 + j];
                #pragma unroll
                for (int i = 0; i < 4; i++)
                    acc[m][i] = fmaf(xv, buf[cur][j].g(i), acc[m][i]);
            }
        }
    }
}

// ============ Type A: quad q — U z-half -> LN -> enc -> dec -> dots ============
template<bool F32>
__device__ void bodyA(float* S, int q,
    const void* __restrict__ x, const void* __restrict__ U_w,
    const void* __restrict__ U_b, const void* __restrict__ ln_w,
    const void* __restrict__ ln_b, const void* __restrict__ enc_w,
    const void* __restrict__ enc_b, const void* __restrict__ dec_w,
    const void* __restrict__ dec_b,
    float* __restrict__ d0, float* __restrict__ diag)
{
    const int rb = 4 * q;
    const int t = threadIdx.x;
    float* xs = S;          // 4 x 384
    float* zs = S + 1536;   // 4 x 384
    float* hid = S + 3072;  // 4 x 192  (+ gh right after = 5th row)
    float* gh = S + 3840;   // 192
    float* part = S + 4032; // up to 5760
    float* sm = S + 9792;   // 24

    #pragma unroll
    for (int m = 0; m < 4; m++) xs[m * 384 + t] = ldg<F32>(x, (rb + m) * FEAT + t);
    if (t < HID) gh[t] = gelu_exact(ldg<F32>(enc_b, t));
    __syncthreads();

    // ---- U z-half: cg=t%96 -> 4 cols (global 384+4cg); kh=t/96 -> K 96kh..+96 ----
    const int cg = t % 96, kh = t / 96;
    const int cL = 4 * cg, cG = ZDIM + cL, kb = 96 * kh;
    float acc[4][4] = {};
    gemmMx4<F32, 96, 4>(U_w, FFN, cG, kb, xs, 384, acc);
    if (kh > 0) {
        float* p = &part[(kh - 1) * 1536 + cg];
        #pragma unroll
        for (int m = 0; m < 4; m++)
            #pragma unroll
            for (int i = 0; i < 4; i++) p[(m * 4 + i) * 96] = acc[m][i];
    }
    __syncthreads();

    float hv[4][4];
    float s1[4] = {0,0,0,0}, s2[4] = {0,0,0,0};
    if (kh == 0) {
        #pragma unroll
        for (int i = 0; i < 4; i++) {
            const float ub = ldg<F32>(U_b, cG + i);
            #pragma unroll
            for (int m = 0; m < 4; m++) {
                float v = acc[m][i] + ub
                        + part[(m * 4 + i) * 96 + cg]
                        + part[1536 + (m * 4 + i) * 96 + cg]
                        + part[3072 + (m * 4 + i) * 96 + cg];
                v = gelu_exact(v);
                hv[m][i] = v;
                s1[m] += v; s2[m] += v * v;
            }
        }
    }
    float S1[4], S2[4];
    block_sum4(s1[0], s1[1], s1[2], s1[3], sm, S1);
    block_sum4(s2[0], s2[1], s2[2], s2[3], sm, S2);
    if (kh == 0) {
        #pragma unroll
        for (int m = 0; m < 4; m++) {
            const float mu = S1[m] * (1.0f / ZDIM);
            const float rs = rsqrtf(S2[m] * (1.0f / ZDIM) - mu * mu + 1e-5f);
            #pragma unroll
            for (int i = 0; i < 4; i++) {
                const int zc = cL + i;
                zs[m * 384 + zc] = (hv[m][i] - mu) * rs * ldg<F32>(ln_w, zc) + ldg<F32>(ln_b, zc);
            }
        }
    }
    __syncthreads();

    // ---- encoder: cgE=t%48 -> 4 cols of 192; khE=t/48 -> K 48khE..+48 ----
    {
        const int cgE = t % 48, khE = t / 48;
        const int cE = 4 * cgE, kbE = 48 * khE;
        float ea[4][4] = {};
        gemmMx4<F32, 48, 4>(enc_w, HID, cE, kbE, zs, 384, ea);
        if (khE > 0) {
            float* p = &part[(khE - 1) * 768 + cgE];
            #pragma unroll
            for (int m = 0; m < 4; m++)
                #pragma unroll
                for (int i = 0; i < 4; i++) p[(m * 4 + i) * 48] = ea[m][i];
        }
        __syncthreads();
        if (khE == 0) {
            #pragma unroll
            for (int i = 0; i < 4; i++) {
                const float ebv = ldg<F32>(enc_b, cE + i);
                #pragma unroll
                for (int m = 0; m < 4; m++) {
                    float v = ea[m][i] + ebv;
                    #pragma unroll
                    for (int kk = 0; kk < 7; kk++)
                        v += part[kk * 768 + (m * 4 + i) * 48 + cgE];
                    hid[m * 192 + cE + i] = gelu_exact(v);
                }
            }
        }
        __syncthreads();
    }

    // ---- decoder: 5-row GEMM (4 hid rows + gh as row 4) ----
    {
        const int cgD = t % 96, khD = t / 96;
        const int cD = 4 * cgD, kbD = 48 * khD;
        float da[5][4] = {};
        gemmMx4<F32, 48, 5>(dec_w, ZDIM, cD, kbD, hid, 192, da);
        if (khD > 0) {
            float* p = &part[(khD - 1) * 1920 + cgD];
            #pragma unroll
            for (int m = 0; m < 5; m++)
                #pragma unroll
                for (int i = 0; i < 4; i++) p[(m * 4 + i) * 96] = da[m][i];
        }
        __syncthreads();
        float pd[4] = {0,0,0,0}, pe[4] = {0,0,0,0};
        if (khD == 0) {
            #pragma unroll
            for (int i = 0; i < 4; i++) {
                const int c = cD + i;
                const float dbv = ldg<F32>(dec_b, c);
                float vc = da[4][i] + dbv;
                #pragma unroll
                for (int kk = 0; kk < 3; kk++)
                    vc += part[kk * 1920 + (16 + i) * 96 + cgD];
                #pragma unroll
                for (int m = 0; m < 4; m++) {
                    float v = da[m][i] + dbv;
                    #pragma unroll
                    for (int kk = 0; kk < 3; kk++)
                        v += part[kk * 1920 + (m * 4 + i) * 96 + cgD];
                    const float zv = zs[m * 384 + c];
                    pd[m] = fmaf(v, zv, pd[m]);
                    pe[m] = fmaf(vc, zv, pe[m]);
                }
            }
        }
        float DG[4], DD[4];
        block_sum4(pd[0], pd[1], pd[2], pd[3], sm, DG);
        block_sum4(pe[0], pe[1], pe[2], pe[3], sm, DD);
        if (t == 0) {
            #pragma unroll
            for (int m = 0; m < 4; m++) { diag[rb + m] = DG[m]; d0[rb + m] = DD[m]; }
        }
    }
}

// ============ Type B: quad q — U xh-half -> Y = xh @ V_w ============
template<bool F32>
__device__ void bodyB(float* S, int q,
    const void* __restrict__ x, const void* __restrict__ U_w,
    const void* __restrict__ U_b, const void* __restrict__ V_w,
    float* __restrict__ Y)
{
    const int rb = 4 * q;
    const int t = threadIdx.x;
    float* xs = S;          // 4 x 384
    float* zs = S + 1536;   // 4 x 384 (xh)
    float* part = S + 4032;

    #pragma unroll
    for (int m = 0; m < 4; m++) xs[m * 384 + t] = ldg<F32>(x, (rb + m) * FEAT + t);
    __syncthreads();

    const int cg = t % 96, kh = t / 96;
    const int cL = 4 * cg, kb = 96 * kh;
    float acc[4][4] = {};
    gemmMx4<F32, 96, 4>(U_w, FFN, cL, kb, xs, 384, acc);
    if (kh > 0) {
        float* p = &part[(kh - 1) * 1536 + cg];
        #pragma unroll
        for (int m = 0; m < 4; m++)
            #pragma unroll
            for (int i = 0; i < 4; i++) p[(m * 4 + i) * 96] = acc[m][i];
    }
    __syncthreads();
    if (kh == 0) {
        #pragma unroll
        for (int i = 0; i < 4; i++) {
            const float ub = ldg<F32>(U_b, cL + i);
            #pragma unroll
            for (int m = 0; m < 4; m++) {
                float v = acc[m][i] + ub
                        + part[(m * 4 + i) * 96 + cg]
                        + part[1536 + (m * 4 + i) * 96 + cg]
                        + part[3072 + (m * 4 + i) * 96 + cg];
                zs[m * 384 + cL + i] = gelu_exact(v);
            }
        }
    }
    __syncthreads();

    // V: same thread mapping; K = 384 full
    float ya[4][4] = {};
    gemmMx4<F32, 96, 4>(V_w, FEAT, cL, kb, zs, 384, ya);
    if (kh > 0) {
        float* p = &part[(kh - 1) * 1536 + cg];
        #pragma unroll
        for (int m = 0; m < 4; m++)
            #pragma unroll
            for (int i = 0; i < 4; i++) p[(m * 4 + i) * 96] = ya[m][i];
    }
    __syncthreads();
    if (kh == 0) {
        #pragma unroll
        for (int m = 0; m < 4; m++) {
            float o[4];
            #pragma unroll
            for (int i = 0; i < 4; i++) {
                o[i] = ya[m][i]
                     + part[(m * 4 + i) * 96 + cg]
                     + part[1536 + (m * 4 + i) * 96 + cg]
                     + part[3072 + (m * 4 + i) * 96 + cg];
            }
            *(float4*)(Y + (size_t)(rb + m) * FEAT + cL) = make_float4(o[0], o[1], o[2], o[3]);
        }
    }
}

// ============ Combine chunk: batch b, cols [96*chunk, 96*chunk+96) ============
// out_i = (baseY + (ed_i - e0_i) * Y_i) / (S - e0_i + ed_i) + V_b
template<bool F32>
__device__ void combine_chunk(float* SP, int b, int chunk,
    const float* __restrict__ d0, const float* __restrict__ diag,
    const float* __restrict__ Y,
    const void* __restrict__ V_b, void* __restrict__ out)
{
    const int cc = chunk * 96;
    const int t = threadIdx.x;
    const int c = t % 96, qq = t / 96;
    float* e0s = SP;           // 128
    float* eds = SP + 128;     // 128
    float* bp  = SP + 256;     // 384
    float* baseY = SP + 640;   // 96
    float* sm  = SP + 736;     // 12

    float d0v = -INFINITY, dgv = -INFINITY;
    if (t < NN) { d0v = d0[b * NN + t]; dgv = diag[b * NN + t]; }
    const float m = block_max(fmaxf(d0v, dgv), sm);
    float e0v = 0.f;
    if (t < NN) {
        e0v = expf(d0v - m);
        e0s[t] = e0v;
        eds[t] = expf(dgv - m);
    }
    const float S = block_sum(e0v, sm);

    const float* Yb = Y + (size_t)b * NN * FEAT + cc + c;
    const int j0 = 32 * qq;
    float p = 0.f;
    for (int jj = 0; jj < 32; jj += 8) {
        float w[8];
        #pragma unroll
        for (int j = 0; j < 8; j++) w[j] = Yb[(size_t)(j0 + jj + j) * FEAT];
        #pragma unroll
        for (int j = 0; j < 8; j++) p = fmaf(e0s[j0 + jj + j], w[j], p);
    }
    bp[qq * 96 + c] = p;
    __syncthreads();
    if (qq == 0) baseY[c] = bp[c] + bp[96 + c] + bp[192 + c] + bp[288 + c];
    __syncthreads();

    const float bY = baseY[c];
    const float vb = ldg<F32>(V_b, cc + c);
    for (int rr = 0; rr < 32; rr += 8) {
        float w[8];
        #pragma unroll
        for (int j = 0; j < 8; j++) w[j] = Yb[(size_t)(j0 + rr + j) * FEAT];
        #pragma unroll
        for (int j = 0; j < 8; j++) {
            const int r = j0 + rr + j;
            const float inv = 1.0f / (S - e0s[r] + eds[r]);
            const float val = (bY + (eds[r] - e0s[r]) * w[j]) * inv + vb;
            stg<F32>(out, (size_t)(b * NN + r) * FEAT + cc + c, val);
        }
    }
}

// ============ Fused kernel: 256 blocks; last 4 finishers per batch combine ====
__global__ __launch_bounds__(384) void k_fused(
    const void* x, const void* U_w, const void* U_b,
    const void* ln_w, const void* ln_b,
    const void* enc_w, const void* enc_b,
    const void* dec_w, const void* dec_b, const void* V_w,
    const void* V_b,
    float* Y, float* d0, float* diag, int* cnt, void* out)
{
    __shared__ float S[SM_TOTAL];   // single pool for all paths
    __shared__ int s_old;
    const int type = blockIdx.x & 1;
    const int q = blockIdx.x >> 1;       // quad 0..127
    const int b = q >> 5;                // batch 0..3 (32 quads/batch)
    const bool f32 = is_f32(ln_w);

    if (f32) {
        if (type == 0) bodyA<true >(S, q, x, U_w, U_b, ln_w, ln_b, enc_w, enc_b, dec_w, dec_b, d0, diag);
        else           bodyB<true >(S, q, x, U_w, U_b, V_w, Y);
    } else {
        if (type == 0) bodyA<false>(S, q, x, U_w, U_b, ln_w, ln_b, enc_w, enc_b, dec_w, dec_b, d0, diag);
        else           bodyB<false>(S, q, x, U_w, U_b, V_w, Y);
    }

    // All this block's global writes are drained by the waitcnt in syncthreads;
    // release-fence then count in. 64 blocks per batch (32 A + 32 B).
    __syncthreads();
    if (threadIdx.x == 0) {
        __threadfence();                       // flush this XCD's L2 (release)
        s_old = atomicAdd(&cnt[b], 1);         // device-scope
    }
    __syncthreads();
    const int old = s_old;                     // block-uniform
    if (old >= 60) {                           // last 4 arrivals -> chunks 0..3
        __threadfence();                       // acquire: invalidate stale caches
        __syncthreads();
        if (f32) combine_chunk<true >(S, b, old - 60, d0, diag, Y, V_b, out);
        else     combine_chunk<false>(S, b, old - 60, d0, diag, Y, V_b, out);
    }
}

extern "C" void kernel_launch(void* const* d_in, const int* in_sizes, int n_in,
                              void* d_out, int out_size, void* d_ws, size_t ws_size,
                              hipStream_t stream) {
    const void* x     = d_in[0];
    const void* U_w   = d_in[1];
    const void* U_b   = d_in[2];
    const void* ln_w  = d_in[3];
    const void* ln_b  = d_in[4];
    const void* enc_w = d_in[5];
    const void* enc_b = d_in[6];
    const void* dec_w = d_in[7];
    const void* dec_b = d_in[8];
    const void* V_w   = d_in[9];
    const void* V_b   = d_in[10];

    float* ws   = (float*)d_ws;
    float* Y    = ws;                     // 512*384  (xh @ V_w, no bias)
    float* d0   = Y + (size_t)BN * FEAT;  // 512
    float* diag = d0 + BN;                // 512
    int*   cnt  = (int*)(diag + BN);      // 4 counters

    hipMemsetAsync(cnt, 0, BB * sizeof(int), stream);
    k_fused<<<2 * (BN / 4), 384, 0, stream>>>(x, U_w, U_b, ln_w, ln_b,
                                              enc_w, enc_b, dec_w, dec_b,
                                              V_w, V_b, Y, d0, diag, cnt, d_out);
}